// Round 8
// baseline (105.669 us; speedup 1.0000x reference)
//
#include <hip/hip_runtime.h>

typedef short s8v __attribute__((ext_vector_type(8)));    // 8 bf16 (raw bits) = 4 VGPRs
typedef float f4v __attribute__((ext_vector_type(4)));    // MFMA accumulator

constexpr int KDIM = 128;
constexpr float INV_COS = 1.0f / 128.0f;

// ---- fp32 -> bf16 (RNE) ----
__device__ inline unsigned short f2bf(float f) {
    unsigned u = __float_as_uint(f);
    u += 0x7fffu + ((u >> 16) & 1u);
    return (unsigned short)(u >> 16);
}

__global__ __launch_bounds__(256) void k_convert(const float* __restrict__ X,
                                                 unsigned short* __restrict__ Xb) {
    int idx = (blockIdx.x * 256 + threadIdx.x) * 4;
    float4 v = *(const float4*)(X + idx);
    ushort4 o;
    o.x = f2bf(v.x); o.y = f2bf(v.y); o.z = f2bf(v.z); o.w = f2bf(v.w);
    *(ushort4*)(Xb + idx) = o;
}

// ---- symmetric 128x128-tile gemm + exp + row/col sums, ALL-DIRECT from L2 ----
// 2 MiB bf16 input is resident in every XCD's 4 MiB L2 -> fragment reads are
// L2 hits. No LDS, no staging, no __syncthreads: every wave independent;
// MFMA interleaves with in-flight global_load_dwordx4 (vmcnt-scheduled).
// Redundancy: each fragment read by 2 waves (wm/wn pairs) -> 128 KB/block,
// 266 MB total @ 34.5 TB/s ~ 7.7 us floor. __launch_bounds__(256,4) caps
// VGPR at 128 so unrolled loads can't kill occupancy (4 blocks/CU).
// partial[row][128] slot map (R3/R5-verified): row r in tile-row b gets
// row-sum slots [2b,128), col-sum slots [0,2b). Exact cover, no atomics.
__global__ __launch_bounds__(256, 4) void k_gemm_rowsum(const unsigned short* __restrict__ Xb,
                                                        float* __restrict__ partial) {
    // linear block id -> upper-triangular (by, bx), 64x64 tile grid
    int rem = blockIdx.x;
    int by = 0;
    while (rem >= 64 - by) { rem -= 64 - by; ++by; }
    const int bx = by + rem;
    const bool offdiag = (bx != by);

    const int wave = threadIdx.x >> 6;
    const int lane = threadIdx.x & 63;
    const int q    = lane >> 4;    // quad 0..3
    const int mrow = lane & 15;
    const int wm   = wave >> 1;    // 2x2 wave grid over 128x128 tile
    const int wn   = wave & 1;
    const int rA = by * 128;
    const int rB = bx * 128;

    // per-lane base pointers: row = (tile base + half*64 + mi*16 + mrow)
    const unsigned short* aBase = Xb + (size_t)(rA + wm * 64 + mrow) * KDIM;
    const unsigned short* bBase = Xb + (size_t)(rB + wn * 64 + mrow) * KDIM;

    f4v acc[4][4];
#pragma unroll
    for (int a = 0; a < 4; ++a)
#pragma unroll
        for (int b = 0; b < 4; ++b)
            acc[a][b] = (f4v){0.f, 0.f, 0.f, 0.f};

#pragma unroll
    for (int ks = 0; ks < 4; ++ks) {               // K-steps of 32
        s8v af[4], bfr[4];
        const int kcol = (ks * 4 + q) * 8;         // 8 bf16 = 16 B chunk
#pragma unroll
        for (int mi = 0; mi < 4; ++mi) {
            af[mi]  = *(const s8v*)&aBase[(size_t)(mi * 16) * KDIM + kcol];
            bfr[mi] = *(const s8v*)&bBase[(size_t)(mi * 16) * KDIM + kcol];
        }
#pragma unroll
        for (int mi = 0; mi < 4; ++mi)
#pragma unroll
            for (int ni = 0; ni < 4; ++ni)
                acc[mi][ni] = __builtin_amdgcn_mfma_f32_16x16x32_bf16(af[mi], bfr[ni], acc[mi][ni], 0, 0, 0);
    }

    // ---- epilogue: e = exp(1 + g/128); lane holds
    // G[wm*64+mi*16+q*4+t][wn*64+ni*16+mrow]
    float rsum[4][4];
    float csum[4] = {0.f, 0.f, 0.f, 0.f};
#pragma unroll
    for (int mi = 0; mi < 4; ++mi)
#pragma unroll
        for (int t = 0; t < 4; ++t)
            rsum[mi][t] = 0.f;

#pragma unroll
    for (int mi = 0; mi < 4; ++mi)
#pragma unroll
        for (int ni = 0; ni < 4; ++ni)
#pragma unroll
            for (int t = 0; t < 4; ++t) {
                float e = __expf(fmaf(acc[mi][ni][t], INV_COS, 1.0f));
                rsum[mi][t] += e;
                csum[ni]    += e;
            }

    // row-sums: reduce across mrow (16 cols) via xor 1,2,4,8
#pragma unroll
    for (int mi = 0; mi < 4; ++mi)
#pragma unroll
        for (int t = 0; t < 4; ++t) {
            float v = rsum[mi][t];
            v += __shfl_xor(v, 1);
            v += __shfl_xor(v, 2);
            v += __shfl_xor(v, 4);
            v += __shfl_xor(v, 8);
            rsum[mi][t] = v;
        }

    // lane c (=mrow) writes row (mi=c>>2, t=c&3) of its quad
    {
        const int c = mrow;
        float outv = 0.f;
#pragma unroll
        for (int mi = 0; mi < 4; ++mi)
#pragma unroll
            for (int t = 0; t < 4; ++t)
                if ((mi * 4 + t) == c) outv = rsum[mi][t];
        int row_loc = wm * 64 + (c >> 2) * 16 + q * 4 + (c & 3);
        partial[(size_t)(rA + row_loc) * 128 + (bx * 2 + wn)] = outv;
    }

    if (offdiag) {
        // col-sums: reduce across q (4 row-groups) via xor 16,32
#pragma unroll
        for (int ni = 0; ni < 4; ++ni) {
            float v = csum[ni];
            v += __shfl_xor(v, 16);
            v += __shfl_xor(v, 32);
            csum[ni] = v;
        }
        if (q == 0) {
#pragma unroll
            for (int ni = 0; ni < 4; ++ni) {
                int col_loc = wn * 64 + ni * 16 + mrow;
                partial[(size_t)(rB + col_loc) * 128 + (by * 2 + wm)] = csum[ni];
            }
        }
    }
}

// ---- finalize 1: one wave per pair, deterministic per-block sums ----
__global__ __launch_bounds__(256) void k_finalize1(const float* __restrict__ X,
                                                   const float* __restrict__ partial,
                                                   float* __restrict__ blocksum) {
    __shared__ float ls[4];
    int wave = threadIdx.x >> 6, lane = threadIdx.x & 63;
    int p = blockIdx.x * 4 + wave;
    int i = 2 * p, j = i + 1;

    float pi = partial[(size_t)i * 128 + lane] + partial[(size_t)i * 128 + 64 + lane];
    float pj = partial[(size_t)j * 128 + lane] + partial[(size_t)j * 128 + 64 + lane];
    float xi0 = X[(size_t)i * 128 + lane], xi1 = X[(size_t)i * 128 + 64 + lane];
    float xj0 = X[(size_t)j * 128 + lane], xj1 = X[(size_t)j * 128 + 64 + lane];
    float dii = xi0 * xi0 + xi1 * xi1;
    float dij = xi0 * xj0 + xi1 * xj1;
    float djj = xj0 * xj0 + xj1 * xj1;

#pragma unroll
    for (int m = 1; m < 64; m <<= 1) {
        pi  += __shfl_xor(pi, m);
        pj  += __shfl_xor(pj, m);
        dii += __shfl_xor(dii, m);
        dij += __shfl_xor(dij, m);
        djj += __shfl_xor(djj, m);
    }
    if (lane == 0) {
        dii *= INV_COS; dij *= INV_COS; djj *= INV_COS;
        float eii = __expf(1.0f + dii);
        float eij = __expf(1.0f + dij);
        float ejj = __expf(1.0f + djj);
        float dissim = (pi - eii - eij) + (pj - eij - ejj);
        float J = __logf(1e-8f + dissim) - dij;
        ls[wave] = (J > 0.f) ? J * J : 0.f;
    }
    __syncthreads();
    if (threadIdx.x == 0)
        blocksum[blockIdx.x] = ls[0] + ls[1] + ls[2] + ls[3];
}

// ---- finalize 2: single block reduces 1024 block sums ----
__global__ __launch_bounds__(256) void k_finalize2(const float* __restrict__ blocksum,
                                                   float* __restrict__ out) {
    __shared__ float ls[4];
    int t = threadIdx.x;
    float s = blocksum[t] + blocksum[t + 256] + blocksum[t + 512] + blocksum[t + 768];
#pragma unroll
    for (int m = 1; m < 64; m <<= 1) s += __shfl_xor(s, m);
    if ((t & 63) == 0) ls[t >> 6] = s;
    __syncthreads();
    if (t == 0) out[0] = (ls[0] + ls[1] + ls[2] + ls[3]) * (1.0f / 16384.0f);
}

extern "C" void kernel_launch(void* const* d_in, const int* in_sizes, int n_in,
                              void* d_out, int out_size, void* d_ws, size_t ws_size,
                              hipStream_t stream) {
    const float* X = (const float*)d_in[0];
    char* ws = (char*)d_ws;
    unsigned short* Xb = (unsigned short*)ws;            // 2 MiB bf16 input
    float* partial  = (float*)(ws + (2u << 20));         // 4 MiB: partial[8192][128]
    float* blocksum = (float*)(ws + (6u << 20));         // 4 KiB
    float* out      = (float*)d_out;

    hipLaunchKernelGGL(k_convert,     dim3(1024), dim3(256), 0, stream, X, Xb);
    hipLaunchKernelGGL(k_gemm_rowsum, dim3(2080), dim3(256), 0, stream, Xb, partial);
    hipLaunchKernelGGL(k_finalize1,   dim3(1024), dim3(256), 0, stream, X, partial, blocksum);
    hipLaunchKernelGGL(k_finalize2,   dim3(1),    dim3(256), 0, stream, blocksum, out);
}

// Round 9
// 80.683 us; speedup vs baseline: 1.3097x; 1.3097x over previous
//
#include <hip/hip_runtime.h>

typedef float f4v __attribute__((ext_vector_type(4)));    // MFMA accumulator

#define GAS __attribute__((address_space(1)))
#define LAS __attribute__((address_space(3)))

constexpr float INV_COS = 1.0f / 128.0f;

// ---- fp32 -> fp8 e4m3 (OCP), packed 4/dword via v_cvt_pk_fp8_f32 ----
__global__ __launch_bounds__(256) void k_convert(const float* __restrict__ X,
                                                 unsigned* __restrict__ X8) {
    int idx = blockIdx.x * 256 + threadIdx.x;        // one dword = 4 fp8
    float4 v = *(const float4*)(X + (size_t)idx * 4);
    int p = __builtin_amdgcn_cvt_pk_fp8_f32(v.x, v.y, 0, false);   // bytes 0,1
    p     = __builtin_amdgcn_cvt_pk_fp8_f32(v.z, v.w, p, true);    // bytes 2,3
    X8[idx] = (unsigned)p;
}

// ---- symmetric 128x128-tile gemm + exp + row/col sums, fp8 staging ----
// R5-verified structure: monolithic staging, ONE vmcnt(0) drain, 64 MFMA per
// barrier. fp8 halves staging bytes AND LDS (32 KiB total -> 5 blocks/CU vs 2).
// Row = 128 fp8 = 8 chunks of 16 B. Slot (r,cph) holds chunk cph^(r&7).
// Fragment (16x16x32 fp8): lane(q=lane>>4, mrow=lane&15) holds
// A[m=mrow][k=q*8+j] -> chunk c=ks*2+(q>>1), byte offset (q&1)*8 (8 B, b64).
// partial[row][128] slot map (R3/R5-verified): row r in tile-row b gets
// row-sum slots [2b,128), col-sum slots [0,2b). Exact cover, no atomics.
__global__ __launch_bounds__(256) void k_gemm_rowsum(const unsigned char* __restrict__ X8,
                                                     float* __restrict__ partial) {
    __shared__ __align__(16) unsigned char ldsA[128 * 128];   // 16 KiB
    __shared__ __align__(16) unsigned char ldsB[128 * 128];   // 16 KiB

    // linear block id -> upper-triangular (by, bx), 64x64 tile grid
    int rem = blockIdx.x;
    int by = 0;
    while (rem >= 64 - by) { rem -= 64 - by; ++by; }
    const int bx = by + rem;
    const bool offdiag = (bx != by);

    const int tid  = threadIdx.x;
    const int wave = tid >> 6;
    const int lane = tid & 63;
    const int rA = by * 128;
    const int rB = bx * 128;

    // ---- staging: each wave loads 4 groups of 8 rows (1 KiB each) per matrix ----
    {
        const int lr8 = lane >> 3;     // row within 8-row group
        const int cph = lane & 7;      // physical 16B-chunk slot
#pragma unroll
        for (int t = 0; t < 4; ++t) {
            int g = wave * 4 + t;                  // 16 groups of 8 rows
            int r_loc = g * 8 + lr8;
            int c_log = cph ^ (r_loc & 7);
            const unsigned char* ga = X8 + (size_t)(rA + r_loc) * 128 + c_log * 16;
            const unsigned char* gb = X8 + (size_t)(rB + r_loc) * 128 + c_log * 16;
            __builtin_amdgcn_global_load_lds((const GAS void*)ga, (LAS void*)&ldsA[g * 1024], 16, 0, 0);
            __builtin_amdgcn_global_load_lds((const GAS void*)gb, (LAS void*)&ldsB[g * 1024], 16, 0, 0);
        }
    }
    __syncthreads();

    const int q    = lane >> 4;    // quad 0..3
    const int mrow = lane & 15;
    const int wm   = wave >> 1;    // 2x2 wave grid over 128x128 tile
    const int wn   = wave & 1;

    f4v acc[4][4];
#pragma unroll
    for (int a = 0; a < 4; ++a)
#pragma unroll
        for (int b = 0; b < 4; ++b)
            acc[a][b] = (f4v){0.f, 0.f, 0.f, 0.f};

#pragma unroll
    for (int ks = 0; ks < 4; ++ks) {               // K-steps of 32
        long af[4], bfr[4];
        const int cp   = (ks * 2 + (q >> 1)) ^ (mrow & 7);
        const int boff = (q & 1) * 8;
#pragma unroll
        for (int mi = 0; mi < 4; ++mi) {
            int ra = wm * 64 + mi * 16 + mrow;     // ra&7 == mrow&7 (bases %8==0)
            int rb = wn * 64 + mi * 16 + mrow;
            af[mi]  = *(const long*)&ldsA[ra * 128 + cp * 16 + boff];
            bfr[mi] = *(const long*)&ldsB[rb * 128 + cp * 16 + boff];
        }
#pragma unroll
        for (int mi = 0; mi < 4; ++mi)
#pragma unroll
            for (int ni = 0; ni < 4; ++ni)
                acc[mi][ni] = __builtin_amdgcn_mfma_f32_16x16x32_fp8_fp8(af[mi], bfr[ni], acc[mi][ni], 0, 0, 0);
    }

    // ---- epilogue: e = exp(1 + g/128); lane holds
    // G[wm*64+mi*16+q*4+t][wn*64+ni*16+mrow]
    float rsum[4][4];
    float csum[4] = {0.f, 0.f, 0.f, 0.f};
#pragma unroll
    for (int mi = 0; mi < 4; ++mi)
#pragma unroll
        for (int t = 0; t < 4; ++t)
            rsum[mi][t] = 0.f;

#pragma unroll
    for (int mi = 0; mi < 4; ++mi)
#pragma unroll
        for (int ni = 0; ni < 4; ++ni)
#pragma unroll
            for (int t = 0; t < 4; ++t) {
                float e = __expf(fmaf(acc[mi][ni][t], INV_COS, 1.0f));
                rsum[mi][t] += e;
                csum[ni]    += e;
            }

    // row-sums: reduce across mrow (16 cols) via xor 1,2,4,8
#pragma unroll
    for (int mi = 0; mi < 4; ++mi)
#pragma unroll
        for (int t = 0; t < 4; ++t) {
            float v = rsum[mi][t];
            v += __shfl_xor(v, 1);
            v += __shfl_xor(v, 2);
            v += __shfl_xor(v, 4);
            v += __shfl_xor(v, 8);
            rsum[mi][t] = v;
        }

    // lane c (=mrow) writes row (mi=c>>2, t=c&3) of its quad
    {
        const int c = mrow;
        float outv = 0.f;
#pragma unroll
        for (int mi = 0; mi < 4; ++mi)
#pragma unroll
            for (int t = 0; t < 4; ++t)
                if ((mi * 4 + t) == c) outv = rsum[mi][t];
        int row_loc = wm * 64 + (c >> 2) * 16 + q * 4 + (c & 3);
        partial[(size_t)(rA + row_loc) * 128 + (bx * 2 + wn)] = outv;
    }

    if (offdiag) {
        // col-sums: reduce across q (4 row-groups) via xor 16,32
#pragma unroll
        for (int ni = 0; ni < 4; ++ni) {
            float v = csum[ni];
            v += __shfl_xor(v, 16);
            v += __shfl_xor(v, 32);
            csum[ni] = v;
        }
        if (q == 0) {
#pragma unroll
            for (int ni = 0; ni < 4; ++ni) {
                int col_loc = wn * 64 + ni * 16 + mrow;
                partial[(size_t)(rB + col_loc) * 128 + (by * 2 + wm)] = csum[ni];
            }
        }
    }
}

// ---- finalize 1: one wave per pair, deterministic per-block sums ----
__global__ __launch_bounds__(256) void k_finalize1(const float* __restrict__ X,
                                                   const float* __restrict__ partial,
                                                   float* __restrict__ blocksum) {
    __shared__ float ls[4];
    int wave = threadIdx.x >> 6, lane = threadIdx.x & 63;
    int p = blockIdx.x * 4 + wave;
    int i = 2 * p, j = i + 1;

    float pi = partial[(size_t)i * 128 + lane] + partial[(size_t)i * 128 + 64 + lane];
    float pj = partial[(size_t)j * 128 + lane] + partial[(size_t)j * 128 + 64 + lane];
    float xi0 = X[(size_t)i * 128 + lane], xi1 = X[(size_t)i * 128 + 64 + lane];
    float xj0 = X[(size_t)j * 128 + lane], xj1 = X[(size_t)j * 128 + 64 + lane];
    float dii = xi0 * xi0 + xi1 * xi1;
    float dij = xi0 * xj0 + xi1 * xj1;
    float djj = xj0 * xj0 + xj1 * xj1;

#pragma unroll
    for (int m = 1; m < 64; m <<= 1) {
        pi  += __shfl_xor(pi, m);
        pj  += __shfl_xor(pj, m);
        dii += __shfl_xor(dii, m);
        dij += __shfl_xor(dij, m);
        djj += __shfl_xor(djj, m);
    }
    if (lane == 0) {
        dii *= INV_COS; dij *= INV_COS; djj *= INV_COS;
        float eii = __expf(1.0f + dii);
        float eij = __expf(1.0f + dij);
        float ejj = __expf(1.0f + djj);
        float dissim = (pi - eii - eij) + (pj - eij - ejj);
        float J = __logf(1e-8f + dissim) - dij;
        ls[wave] = (J > 0.f) ? J * J : 0.f;
    }
    __syncthreads();
    if (threadIdx.x == 0)
        blocksum[blockIdx.x] = ls[0] + ls[1] + ls[2] + ls[3];
}

// ---- finalize 2: single block reduces 1024 block sums ----
__global__ __launch_bounds__(256) void k_finalize2(const float* __restrict__ blocksum,
                                                   float* __restrict__ out) {
    __shared__ float ls[4];
    int t = threadIdx.x;
    float s = blocksum[t] + blocksum[t + 256] + blocksum[t + 512] + blocksum[t + 768];
#pragma unroll
    for (int m = 1; m < 64; m <<= 1) s += __shfl_xor(s, m);
    if ((t & 63) == 0) ls[t >> 6] = s;
    __syncthreads();
    if (t == 0) out[0] = (ls[0] + ls[1] + ls[2] + ls[3]) * (1.0f / 16384.0f);
}

extern "C" void kernel_launch(void* const* d_in, const int* in_sizes, int n_in,
                              void* d_out, int out_size, void* d_ws, size_t ws_size,
                              hipStream_t stream) {
    const float* X = (const float*)d_in[0];
    char* ws = (char*)d_ws;
    unsigned* X8 = (unsigned*)ws;                        // 1 MiB fp8 input
    float* partial  = (float*)(ws + (1u << 20));         // 4 MiB: partial[8192][128]
    float* blocksum = (float*)(ws + (5u << 20));         // 4 KiB
    float* out      = (float*)d_out;

    hipLaunchKernelGGL(k_convert,     dim3(1024), dim3(256), 0, stream, X, X8);
    hipLaunchKernelGGL(k_gemm_rowsum, dim3(2080), dim3(256), 0, stream, (const unsigned char*)X8, partial);
    hipLaunchKernelGGL(k_finalize1,   dim3(1024), dim3(256), 0, stream, X, partial, blocksum);
    hipLaunchKernelGGL(k_finalize2,   dim3(1),    dim3(256), 0, stream, blocksum, out);
}